// Round 1
// baseline (845.506 us; speedup 1.0000x reference)
//
#include <hip/hip_runtime.h>

#define TT 256
#define BB 32
#define NN 128
#define HH 128

typedef __attribute__((ext_vector_type(8))) short short8;
typedef __attribute__((ext_vector_type(4))) float f32x4;

__device__ __forceinline__ short f2bf(float f) {
    unsigned u = __builtin_bit_cast(unsigned, f);
    unsigned r = u + 0x7FFFu + ((u >> 16) & 1u);
    return (short)(r >> 16);
}
__device__ __forceinline__ float b2f(short s) {
    unsigned u = ((unsigned)(unsigned short)s) << 16;
    return __builtin_bit_cast(float, u);
}
__device__ __forceinline__ float frcp(float x) { return __builtin_amdgcn_rcpf(x); }
__device__ __forceinline__ float sigm(float x) { return frcp(1.f + __expf(-x)); }
__device__ __forceinline__ float tanhfast(float x) {
    float ax = fabsf(x);
    float e = __expf(-2.f * ax);
    float t = (1.f - e) * frcp(1.f + e);
    return x < 0.f ? -t : t;
}
__device__ __forceinline__ float softplusf(float z) {
    // log1p(exp(z)), overflow-stable
    return fmaxf(z, 0.f) + __logf(1.f + __expf(-fabsf(z)));
}

// Block: 512 threads = 8 waves, owns 16 sequences (one batch b, neurons n0..n0+15).
// Wave w owns units u = w*16 + (lane&15); gates i,f,g,o for that u live in the
// same thread (col-tiles w, 8+w, 16+w, 24+w of the 16x512 gate matrix).
__global__ __launch_bounds__(512, 2) void lstm_kernel(
    const float* __restrict__ in, const float* __restrict__ W_ih,
    const float* __restrict__ b_ih, const float* __restrict__ W_hh,
    const float* __restrict__ b_hh, const float* __restrict__ Wl,
    const float* __restrict__ bl, const float* __restrict__ W1,
    const float* __restrict__ b1, const float* __restrict__ W2,
    const float* __restrict__ b2, float* __restrict__ out)
{
    __shared__ __align__(16) short h_hi[16 * 136];   // bf16 hi, padded stride 136
    __shared__ __align__(16) short h_lo[16 * 136];   // bf16 lo
    __shared__ __align__(16) float h_f32[16 * 128];  // exact h for gat dots
    __shared__ __align__(16) float out_prev[16];
    __shared__ __align__(16) float gat_lds[16 * 4];  // [s][{g,a,th,pad}]
    __shared__ __align__(16) float wl_lds[3 * 128];
    __shared__ float bl_lds[4];

    const int tid = threadIdx.x;
    const int w = tid >> 6, l = tid & 63;
    const int lrow = l & 15, lkhi = l >> 4;
    const int u = w * 16 + lrow;
    const int bid = blockIdx.x;
    const int b = bid >> 3, n0 = (bid & 7) << 4;

    // ---- one-time init ----
    // W_hh.T fragments (hi/lo bf16 split), resident in registers for all steps.
    short8 bfh[4][4], bfl[4][4];
#pragma unroll
    for (int g = 0; g < 4; ++g)
#pragma unroll
        for (int kt = 0; kt < 4; ++kt) {
            const float* src = W_hh + (g * HH + u) * HH + kt * 32 + lkhi * 8;
            short8 hh, ll;
#pragma unroll
            for (int i = 0; i < 8; ++i) {
                float f = src[i];
                short h = f2bf(f);
                hh[i] = h;
                ll[i] = f2bf(f - b2f(h));
            }
            bfh[g][kt] = hh;
            bfl[g][kt] = ll;
        }

    float wx[4], wo[4], bs[4];
#pragma unroll
    for (int g = 0; g < 4; ++g) {
        int j = g * HH + u;
        wx[g] = W_ih[2 * j];
        wo[g] = W_ih[2 * j + 1];
        bs[g] = b_ih[j] + b_hh[j];
    }

    for (int i = tid; i < 3 * HH; i += 512) wl_lds[i] = Wl[i];
    if (tid < 3) bl_lds[tid] = bl[tid];
    for (int i = tid; i < 16 * 136; i += 512) { h_hi[i] = 0; h_lo[i] = 0; }
    for (int i = tid; i < 16 * 128; i += 512) h_f32[i] = 0.f;

    // per-neuron MLP is affine in x: out_lin = A_n*x + C_n
    float An = 0.f, Cn = 0.f;
    if (w == 1 && l < 16) {
        int n = n0 + l;
#pragma unroll
        for (int k = 0; k < 10; ++k) {
            An = fmaf(W1[n * 10 + k], W2[n * 10 + k], An);
            Cn = fmaf(b1[n * 10 + k], W2[n * 10 + k], Cn);
        }
        Cn += b2[n];
        // t = 0 output
        float x0 = in[b * NN + n0 + l];
        float ol = fmaf(x0, An, Cn);
        float o0 = softplusf(ol - 1.f);
        out[b * NN + n0 + l] = o0;
        out_prev[l] = o0;
    }
    float c[4] = {0.f, 0.f, 0.f, 0.f};
    __syncthreads();

    for (int t = 1; t < TT; ++t) {
        // ---- phase 1: reads (h_{t-1}, out_{t-1}, x_t) ----
        short8 ah[4], al[4];
#pragma unroll
        for (int kt = 0; kt < 4; ++kt) {
            ah[kt] = *(const short8*)(h_hi + lrow * 136 + kt * 32 + lkhi * 8);
            al[kt] = *(const short8*)(h_lo + lrow * 136 + kt * 32 + lkhi * 8);
        }
        const float* xrow = in + (t * BB + b) * NN + n0;
        f32x4 x4 = *(const f32x4*)(xrow + lkhi * 4);
        f32x4 op4 = *(const f32x4*)(out_prev + lkhi * 4);
        float xs = 0.f;
        if (w == 1 && l < 16) xs = xrow[l];

        // ---- phase 2: compute ----
        // gates = h @ W_hh.T via split bf16 MFMA: Ah*Bh + Ah*Bl + Al*Bh (~fp32)
        f32x4 acc[4];
#pragma unroll
        for (int g = 0; g < 4; ++g) {
            f32x4 a0 = {0.f, 0.f, 0.f, 0.f};
#pragma unroll
            for (int kt = 0; kt < 4; ++kt) {
                a0 = __builtin_amdgcn_mfma_f32_16x16x32_bf16(ah[kt], bfh[g][kt], a0, 0, 0, 0);
                a0 = __builtin_amdgcn_mfma_f32_16x16x32_bf16(ah[kt], bfl[g][kt], a0, 0, 0, 0);
                a0 = __builtin_amdgcn_mfma_f32_16x16x32_bf16(al[kt], bfh[g][kt], a0, 0, 0, 0);
            }
            acc[g] = a0;
        }

        // gat_{t-1} = h_{t-1} @ Wl.T + bl in exact fp32: 48 dots, 6 per wave
#pragma unroll
        for (int dd = 0; dd < 6; ++dd) {
            int d = w * 6 + dd;
            int s = d / 3, j = d - 3 * s;
            float p = fmaf(h_f32[s * 128 + l], wl_lds[j * 128 + l],
                           h_f32[s * 128 + l + 64] * wl_lds[j * 128 + l + 64]);
#pragma unroll
            for (int off = 32; off; off >>= 1) p += __shfl_xor(p, off);
            if (l == 0) gat_lds[s * 4 + j] = p + bl_lds[j];
        }

        // thread-local gate recombination + cell update
        float hnew[4];
#pragma unroll
        for (int r = 0; r < 4; ++r) {
            float gi = acc[0][r] + fmaf(wx[0], x4[r], fmaf(wo[0], op4[r], bs[0]));
            float gf = acc[1][r] + fmaf(wx[1], x4[r], fmaf(wo[1], op4[r], bs[1]));
            float gg = acc[2][r] + fmaf(wx[2], x4[r], fmaf(wo[2], op4[r], bs[2]));
            float go = acc[3][r] + fmaf(wx[3], x4[r], fmaf(wo[3], op4[r], bs[3]));
            float I = sigm(gi), F = sigm(gf), G = tanhfast(gg), O = sigm(go);
            c[r] = fmaf(F, c[r], I * G);
            hnew[r] = O * tanhfast(c[r]);
        }
        __syncthreads();  // barrier B: h reads done; gat_lds written

        // ---- phase 3: writes + output head ----
#pragma unroll
        for (int r = 0; r < 4; ++r) {
            int s = lkhi * 4 + r;
            float hv = hnew[r];
            short hi = f2bf(hv);
            h_hi[s * 136 + u] = hi;
            h_lo[s * 136 + u] = f2bf(hv - b2f(hi));
            h_f32[s * 128 + u] = hv;
        }
        if (w == 1 && l < 16) {
            f32x4 gv = *(const f32x4*)(gat_lds + l * 4);
            float gp = gv[0], ap = gv[1], tp = gv[2];
            if (t == 1) { gp = 1.f; ap = 1.f; tp = 1.f; }
            float ol = fmaf(xs, An, Cn);
            float z = ap * (ol - tp);
            float o = gp * softplusf(z) * frcp(ap);
            out[(t * BB + b) * NN + n0 + l] = o;
            out_prev[l] = o;
        }
        __syncthreads();  // barrier C: h_{t}, out_t visible for next step
    }
}

extern "C" void kernel_launch(void* const* d_in, const int* in_sizes, int n_in,
                              void* d_out, int out_size, void* d_ws, size_t ws_size,
                              hipStream_t stream) {
    const float* in   = (const float*)d_in[0];
    const float* W_ih = (const float*)d_in[1];
    const float* b_ih = (const float*)d_in[2];
    const float* W_hh = (const float*)d_in[3];
    const float* b_hh = (const float*)d_in[4];
    const float* Wl   = (const float*)d_in[5];
    const float* bl   = (const float*)d_in[6];
    const float* W1   = (const float*)d_in[7];
    const float* b1   = (const float*)d_in[8];
    const float* W2   = (const float*)d_in[9];
    const float* b2   = (const float*)d_in[10];
    float* out = (float*)d_out;

    lstm_kernel<<<dim3(256), dim3(512), 0, stream>>>(
        in, W_ih, b_ih, W_hh, b_hh, Wl, bl, W1, b1, W2, b2, out);
}

// Round 2
// 537.114 us; speedup vs baseline: 1.5742x; 1.5742x over previous
//
#include <hip/hip_runtime.h>

#define TT 256
#define BB 32
#define NN 128
#define HH 128
#define HSTR 136  // shorts; 272B rows -> 16B aligned, near-uniform bank spread

typedef __attribute__((ext_vector_type(8))) short short8;
typedef __attribute__((ext_vector_type(4))) float f32x4;

__device__ __forceinline__ short f2bf(float f) {
    unsigned u = __builtin_bit_cast(unsigned, f);
    unsigned r = u + 0x7FFFu + ((u >> 16) & 1u);
    return (short)(r >> 16);
}
__device__ __forceinline__ float b2f(short s) {
    unsigned u = ((unsigned)(unsigned short)s) << 16;
    return __builtin_bit_cast(float, u);
}
__device__ __forceinline__ float frcp(float x) { return __builtin_amdgcn_rcpf(x); }
__device__ __forceinline__ float sigm(float x) { return frcp(1.f + __expf(-x)); }
__device__ __forceinline__ float tanhfast(float x) {
    float ax = fabsf(x);
    float e = __expf(-2.f * ax);
    float t = (1.f - e) * frcp(1.f + e);
    return x < 0.f ? -t : t;
}
__device__ __forceinline__ float softplusf(float z) {
    return fmaxf(z, 0.f) + __logf(1.f + __expf(-fabsf(z)));
}

// Block: 512 threads = 8 waves, 16 sequences (batch b, neurons n0..n0+15).
// Wave w owns gate columns for units u = w*16 + (lane&15).
// Single barrier per step: h double-buffered; x/out staged in LDS.
// Wave 0 additionally computes gat = h@Wl.T as a 5th MFMA tile + output head.
__global__ __launch_bounds__(512, 2) void lstm_kernel(
    const float* __restrict__ in, const float* __restrict__ W_ih,
    const float* __restrict__ b_ih, const float* __restrict__ W_hh,
    const float* __restrict__ b_hh, const float* __restrict__ Wl,
    const float* __restrict__ bl, const float* __restrict__ W1,
    const float* __restrict__ b1, const float* __restrict__ W2,
    const float* __restrict__ b2, float* __restrict__ out)
{
    __shared__ __align__(16) short h_hi[2][16 * HSTR];
    __shared__ __align__(16) short h_lo[2][16 * HSTR];
    __shared__ __align__(16) float x_lds[TT * 16];      // all timesteps' inputs
    __shared__ __align__(16) float out_stage[TT * 16];  // all timesteps' outputs

    const int tid = threadIdx.x;
    const int w = tid >> 6, l = tid & 63;
    const int lrow = l & 15, lkhi = l >> 4;
    const int u = w * 16 + lrow;
    const int bid = blockIdx.x;
    const int b = bid >> 3, n0 = (bid & 7) << 4;

    // ---- stage x: in[t][b][n0..n0+15] -> x_lds[t][j] ----
    for (int i = tid; i < TT * 16; i += 512) {
        int t = i >> 4, j = i & 15;
        x_lds[i] = in[(t * BB + b) * NN + n0 + j];
    }

    // ---- W_hh.T fragments (hi/lo bf16 split), register/AGPR resident ----
    short8 bfh[4][4], bfl[4][4];
#pragma unroll
    for (int g = 0; g < 4; ++g)
#pragma unroll
        for (int kt = 0; kt < 4; ++kt) {
            const float* src = W_hh + (g * HH + u) * HH + kt * 32 + lkhi * 8;
            short8 hh, ll;
#pragma unroll
            for (int i = 0; i < 8; ++i) {
                float f = src[i];
                short h = f2bf(f);
                hh[i] = h;
                ll[i] = (short)(__builtin_bit_cast(unsigned, f - b2f(h)) >> 16);
            }
            bfh[g][kt] = hh;
            bfl[g][kt] = ll;
        }

    // Wl tile (cols 0..2 of a 16-wide tile), hi/lo split — used by wave 0 only
    short8 wlh[4], wll[4];
#pragma unroll
    for (int kt = 0; kt < 4; ++kt) {
        short8 hh, ll;
#pragma unroll
        for (int i = 0; i < 8; ++i) {
            float f = (lrow < 3) ? Wl[lrow * HH + kt * 32 + lkhi * 8 + i] : 0.f;
            short h = f2bf(f);
            hh[i] = h;
            ll[i] = (short)(__builtin_bit_cast(unsigned, f - b2f(h)) >> 16);
        }
        wlh[kt] = hh;
        wll[kt] = ll;
    }
    const float bl0 = bl[0], bl1 = bl[1], bl2 = bl[2];

    float wx[4], wo[4], bs[4];
#pragma unroll
    for (int g = 0; g < 4; ++g) {
        int j = g * HH + u;
        wx[g] = W_ih[2 * j];
        wo[g] = W_ih[2 * j + 1];
        bs[g] = b_ih[j] + b_hh[j];
    }

    for (int i = tid; i < 16 * HSTR; i += 512) {
        h_hi[0][i] = 0; h_hi[1][i] = 0;
        h_lo[0][i] = 0; h_lo[1][i] = 0;
    }

    // per-neuron MLP is affine in x: out_lin = An*x + Cn  (wave0 head lanes)
    float An = 0.f, Cn = 0.f;
    if (w == 0 && l < 16) {
        int n = n0 + l;
#pragma unroll
        for (int k = 0; k < 10; ++k) {
            An = fmaf(W1[n * 10 + k], W2[n * 10 + k], An);
            Cn = fmaf(b1[n * 10 + k], W2[n * 10 + k], Cn);
        }
        Cn += b2[n];
        float x0 = in[b * NN + n0 + l];
        float o0 = softplusf(fmaf(x0, An, Cn) - 1.f);
        out_stage[l] = o0;
    }
    float c[4] = {0.f, 0.f, 0.f, 0.f};
    __syncthreads();

#pragma unroll 2
    for (int t = 1; t < TT; ++t) {
        const int p = (t - 1) & 1;

        // ---- reads: h_{t-1} frags, x_t, out_{t-1} ----
        short8 ah[4], al[4];
#pragma unroll
        for (int kt = 0; kt < 4; ++kt) {
            ah[kt] = *(const short8*)(&h_hi[p][lrow * HSTR + kt * 32 + lkhi * 8]);
            al[kt] = *(const short8*)(&h_lo[p][lrow * HSTR + kt * 32 + lkhi * 8]);
        }
        f32x4 x4  = *(const f32x4*)(x_lds + t * 16 + lkhi * 4);
        f32x4 op4 = *(const f32x4*)(out_stage + (t - 1) * 16 + lkhi * 4);

        // ---- gates = h @ W_hh.T (hi/lo split: ~fp32 accurate) ----
        f32x4 acc[4];
#pragma unroll
        for (int g = 0; g < 4; ++g) {
            f32x4 a0 = {0.f, 0.f, 0.f, 0.f};
#pragma unroll
            for (int kt = 0; kt < 4; ++kt) {
                a0 = __builtin_amdgcn_mfma_f32_16x16x32_bf16(ah[kt], bfh[g][kt], a0, 0, 0, 0);
                a0 = __builtin_amdgcn_mfma_f32_16x16x32_bf16(ah[kt], bfl[g][kt], a0, 0, 0, 0);
                a0 = __builtin_amdgcn_mfma_f32_16x16x32_bf16(al[kt], bfh[g][kt], a0, 0, 0, 0);
            }
            acc[g] = a0;
        }

        // ---- wave 0: gat_{t-1} = h_{t-1} @ Wl.T as 5th MFMA tile ----
        f32x4 acc5 = {0.f, 0.f, 0.f, 0.f};
        if (w == 0) {
#pragma unroll
            for (int kt = 0; kt < 4; ++kt) {
                acc5 = __builtin_amdgcn_mfma_f32_16x16x32_bf16(ah[kt], wlh[kt], acc5, 0, 0, 0);
                acc5 = __builtin_amdgcn_mfma_f32_16x16x32_bf16(ah[kt], wll[kt], acc5, 0, 0, 0);
                acc5 = __builtin_amdgcn_mfma_f32_16x16x32_bf16(al[kt], wlh[kt], acc5, 0, 0, 0);
            }
        }

        // ---- gate recombination + cell update (thread-local) ----
        float hnew[4];
#pragma unroll
        for (int r = 0; r < 4; ++r) {
            float gi = acc[0][r] + fmaf(wx[0], x4[r], fmaf(wo[0], op4[r], bs[0]));
            float gf = acc[1][r] + fmaf(wx[1], x4[r], fmaf(wo[1], op4[r], bs[1]));
            float gg = acc[2][r] + fmaf(wx[2], x4[r], fmaf(wo[2], op4[r], bs[2]));
            float go = acc[3][r] + fmaf(wx[3], x4[r], fmaf(wo[3], op4[r], bs[3]));
            float I = sigm(gi), F = sigm(gf), G = tanhfast(gg), O = sigm(go);
            c[r] = fmaf(F, c[r], I * G);
            hnew[r] = O * tanhfast(c[r]);
        }

        // ---- write h_t into the other buffer (no barrier needed before) ----
#pragma unroll
        for (int r = 0; r < 4; ++r) {
            int s = lkhi * 4 + r;
            float hv = hnew[r];
            short hi = f2bf(hv);
            h_hi[p ^ 1][s * HSTR + u] = hi;
            h_lo[p ^ 1][s * HSTR + u] =
                (short)(__builtin_bit_cast(unsigned, hv - b2f(hi)) >> 16);
        }

        // ---- wave 0: output head (in-wave shuffles, no barrier) ----
        if (w == 0) {
            float gp = 1.f, ap = 1.f, tp = 1.f;
            int base = ((l >> 2) << 4) & 63;
#pragma unroll
            for (int r = 0; r < 4; ++r) {
                float gv = __shfl(acc5[r], base + 0);
                float av = __shfl(acc5[r], base + 1);
                float tv = __shfl(acc5[r], base + 2);
                if ((l & 3) == r) { gp = gv; ap = av; tp = tv; }
            }
            gp += bl0; ap += bl1; tp += bl2;
            if (t == 1) { gp = 1.f; ap = 1.f; tp = 1.f; }
            if (l < 16) {
                float ol = fmaf(x_lds[t * 16 + l], An, Cn);
                float o = gp * softplusf(ap * (ol - tp)) * frcp(ap);
                out_stage[t * 16 + l] = o;
            }
        }

        __syncthreads();  // single barrier: h_t, out_t visible for step t+1
    }

    // ---- flush staged outputs: coalesced, full-line writes ----
#pragma unroll
    for (int i = 0; i < 2; ++i) {
        int idx = tid + i * 512;          // 0..1023 vec4s
        int t = idx >> 2;
        int j4 = (idx & 3) << 2;
        f32x4 v = *(const f32x4*)(out_stage + t * 16 + j4);
        *(f32x4*)(out + (t * BB + b) * NN + n0 + j4) = v;
    }
}

extern "C" void kernel_launch(void* const* d_in, const int* in_sizes, int n_in,
                              void* d_out, int out_size, void* d_ws, size_t ws_size,
                              hipStream_t stream) {
    const float* in   = (const float*)d_in[0];
    const float* W_ih = (const float*)d_in[1];
    const float* b_ih = (const float*)d_in[2];
    const float* W_hh = (const float*)d_in[3];
    const float* b_hh = (const float*)d_in[4];
    const float* Wl   = (const float*)d_in[5];
    const float* bl   = (const float*)d_in[6];
    const float* W1   = (const float*)d_in[7];
    const float* b1   = (const float*)d_in[8];
    const float* W2   = (const float*)d_in[9];
    const float* b2   = (const float*)d_in[10];
    float* out = (float*)d_out;

    lstm_kernel<<<dim3(256), dim3(512), 0, stream>>>(
        in, W_ih, b_ih, W_hh, b_hh, Wl, bl, W1, b1, W2, b2, out);
}

// Round 3
// 515.572 us; speedup vs baseline: 1.6399x; 1.0418x over previous
//
#include <hip/hip_runtime.h>

#define TT 256
#define BB 32
#define NN 128
#define HH 128
#define HSTR 136  // shorts; 272B rows -> 16B-aligned b128 frag reads

typedef __attribute__((ext_vector_type(8))) short short8;
typedef __attribute__((ext_vector_type(4))) float f32x4;

__device__ __forceinline__ short f2bf_rne(float f) {
    unsigned u = __builtin_bit_cast(unsigned, f);
    unsigned r = u + 0x7FFFu + ((u >> 16) & 1u);
    return (short)(r >> 16);
}
__device__ __forceinline__ short f2bf_tr(float f) {
    return (short)(__builtin_bit_cast(unsigned, f) >> 16);
}
__device__ __forceinline__ float b2f(short s) {
    unsigned u = ((unsigned)(unsigned short)s) << 16;
    return __builtin_bit_cast(float, u);
}
__device__ __forceinline__ float frcp(float x) { return __builtin_amdgcn_rcpf(x); }
__device__ __forceinline__ float sigm(float x) { return frcp(1.f + __expf(-x)); }
__device__ __forceinline__ float tanh2(float x) {
    // tanh(x) = 2*sigmoid(2x) - 1 ; inf-safe via v_rcp(inf)=0
    return fmaf(2.f, frcp(1.f + __expf(-2.f * x)), -1.f);
}
__device__ __forceinline__ float softplusf(float z) {
    return fmaxf(z, 0.f) + __logf(1.f + __expf(-fabsf(z)));
}

// Block: 512 threads = 8 waves, 16 sequences (batch b, neurons n0..n0+15).
// Wave w owns gate columns for units u = w*16 + (lane&15).
// x2 path (wx*x + wo*out_prev + bias) folded into MFMA as a 5th K-tile.
// Head (gat = Wl @ h^T) on wave 0 via swapped operands: lane s holds g,a,th.
__global__ __launch_bounds__(512, 2) void lstm_kernel(
    const float* __restrict__ in, const float* __restrict__ W_ih,
    const float* __restrict__ b_ih, const float* __restrict__ W_hh,
    const float* __restrict__ b_hh, const float* __restrict__ Wl,
    const float* __restrict__ bl, const float* __restrict__ W1,
    const float* __restrict__ b1, const float* __restrict__ W2,
    const float* __restrict__ b2, float* __restrict__ out)
{
    __shared__ __align__(16) short h_hi[2][16 * HSTR];
    __shared__ __align__(16) short h_lo[2][16 * HSTR];
    __shared__ __align__(16) float x_lds[TT * 16];
    __shared__ __align__(16) float out_stage[TT * 16];
    __shared__ __align__(16) short wl_stage[64 * 32];  // Wl frags, lane-major
    __shared__ unsigned op_pack[2][16];                // out_prev bf16 hi|lo

    const int tid = threadIdx.x;
    const int w = tid >> 6, l = tid & 63;
    const int lrow = l & 15, lkhi = l >> 4;
    const int u = w * 16 + lrow;
    const int bid = blockIdx.x;
    const int b = bid >> 3, n0 = (bid & 7) << 4;

    // ---- stage x ----
    for (int i = tid; i < TT * 16; i += 512) {
        int t = i >> 4, j = i & 15;
        x_lds[i] = in[(t * BB + b) * NN + n0 + j];
    }

    // ---- W_hh.T fragments (hi/lo bf16 split), register resident ----
    short8 bfh[4][4], bfl[4][4];
#pragma unroll
    for (int g = 0; g < 4; ++g)
#pragma unroll
        for (int kt = 0; kt < 4; ++kt) {
            const float* src = W_hh + (g * HH + u) * HH + kt * 32 + lkhi * 8;
            short8 hh, ll;
#pragma unroll
            for (int i = 0; i < 8; ++i) {
                float f = src[i];
                short h = f2bf_rne(f);
                hh[i] = h;
                ll[i] = f2bf_tr(f - b2f(h));
            }
            bfh[g][kt] = hh;
            bfl[g][kt] = ll;
        }

    // ---- ext tile B-frags: [wx, wo, bs_hi, bs_lo] per gate (lanes l<16) ----
    short8 bexth[4] = {}, bextl[4] = {};
    if (l < 16) {
#pragma unroll
        for (int g = 0; g < 4; ++g) {
            int j = g * HH + u;  // u == w*16 + l here
            float wxv = W_ih[2 * j], wov = W_ih[2 * j + 1];
            float bsv = b_ih[j] + b_hh[j];
            short wxh = f2bf_rne(wxv), woh = f2bf_rne(wov), bsh = f2bf_rne(bsv);
            bexth[g][0] = wxh;
            bexth[g][1] = woh;
            bexth[g][2] = bsh;
            bexth[g][3] = f2bf_tr(bsv - b2f(bsh));
            bextl[g][0] = f2bf_tr(wxv - b2f(wxh));
            bextl[g][1] = f2bf_tr(wov - b2f(woh));
        }
    }
    // ext tile A-frags: [x, op, 1, 1] built per step; constants set once
    short8 aexth = {}, aextl = {};
    if (l < 16) {
        aexth[2] = (short)0x3F80;  // 1.0 bf16
        aexth[3] = (short)0x3F80;
    }

    // ---- wave0: Wl frags -> LDS (rows >=3 zero) ----
    if (w == 0) {
#pragma unroll
        for (int kt = 0; kt < 4; ++kt) {
            short8 wlv;
#pragma unroll
            for (int i = 0; i < 8; ++i) {
                float f = (lrow < 3) ? Wl[lrow * HH + kt * 32 + lkhi * 8 + i] : 0.f;
                wlv[i] = f2bf_rne(f);
            }
            *(short8*)(wl_stage + l * 32 + kt * 8) = wlv;
        }
    }
    f32x4 blv = {bl[0], bl[1], bl[2], 0.f};

    // ---- per-neuron affine MLP coeffs + t=0 output (wave0 head lanes) ----
    float An = 0.f, Cn = 0.f;
    if (w == 0 && l < 16) {
        int n = n0 + l;
#pragma unroll
        for (int k = 0; k < 10; ++k) {
            An = fmaf(W1[n * 10 + k], W2[n * 10 + k], An);
            Cn = fmaf(b1[n * 10 + k], W2[n * 10 + k], Cn);
        }
        Cn += b2[n];
        float x0 = in[b * NN + n0 + l];
        float o0 = softplusf(fmaf(x0, An, Cn) - 1.f);
        out_stage[l] = o0;
        short oh = f2bf_tr(o0);
        unsigned olo = (unsigned)(unsigned short)f2bf_tr(o0 - b2f(oh));
        op_pack[0][l] = (unsigned)(unsigned short)oh | (olo << 16);
    }

    for (int i = tid; i < 16 * HSTR; i += 512) {
        h_hi[0][i] = 0; h_hi[1][i] = 0;
        h_lo[0][i] = 0; h_lo[1][i] = 0;
    }
    float c[4] = {0.f, 0.f, 0.f, 0.f};
    __syncthreads();

#pragma unroll 2
    for (int t = 1; t < TT; ++t) {
        const int p = (t - 1) & 1;

        // ---- h_{t-1} fragments ----
        short8 ah[4], al[4];
#pragma unroll
        for (int kt = 0; kt < 4; ++kt) {
            ah[kt] = *(const short8*)(&h_hi[p][lrow * HSTR + kt * 32 + lkhi * 8]);
            al[kt] = *(const short8*)(&h_lo[p][lrow * HSTR + kt * 32 + lkhi * 8]);
        }

        // ---- build ext A-frag: [x_t, out_{t-1}, 1, 1] hi/lo ----
        if (l < 16) {
            float xv = x_lds[t * 16 + l];
            short xh = f2bf_tr(xv);
            short xlo = f2bf_tr(xv - b2f(xh));
            unsigned ov = op_pack[p][l];
            aexth[0] = xh;
            aexth[1] = (short)ov;
            aextl[0] = xlo;
            aextl[1] = (short)(ov >> 16);
        }

        // ---- gates: ext tile first (hides ds_read latency), then K=128 ----
        f32x4 acc[4];
#pragma unroll
        for (int g = 0; g < 4; ++g) {
            f32x4 a0 = {0.f, 0.f, 0.f, 0.f};
            a0 = __builtin_amdgcn_mfma_f32_16x16x32_bf16(aexth, bexth[g], a0, 0, 0, 0);
            a0 = __builtin_amdgcn_mfma_f32_16x16x32_bf16(aextl, bexth[g], a0, 0, 0, 0);
            a0 = __builtin_amdgcn_mfma_f32_16x16x32_bf16(aexth, bextl[g], a0, 0, 0, 0);
#pragma unroll
            for (int kt = 0; kt < 4; ++kt) {
                a0 = __builtin_amdgcn_mfma_f32_16x16x32_bf16(ah[kt], bfh[g][kt], a0, 0, 0, 0);
                a0 = __builtin_amdgcn_mfma_f32_16x16x32_bf16(ah[kt], bfl[g][kt], a0, 0, 0, 0);
                a0 = __builtin_amdgcn_mfma_f32_16x16x32_bf16(al[kt], bfh[g][kt], a0, 0, 0, 0);
            }
            acc[g] = a0;
        }

        // ---- wave0: gat via swapped operands: lane s holds g,a,th in rows ----
        f32x4 acc5 = blv;
        if (w == 0) {
#pragma unroll
            for (int kt = 0; kt < 4; ++kt) {
                short8 wlv = *(const short8*)(wl_stage + l * 32 + kt * 8);
                acc5 = __builtin_amdgcn_mfma_f32_16x16x32_bf16(wlv, ah[kt], acc5, 0, 0, 0);
                acc5 = __builtin_amdgcn_mfma_f32_16x16x32_bf16(wlv, al[kt], acc5, 0, 0, 0);
            }
        }

        // ---- gate nonlinearities + cell update + h_t write ----
#pragma unroll
        for (int r = 0; r < 4; ++r) {
            float I = sigm(acc[0][r]);
            float F = sigm(acc[1][r]);
            float G = tanh2(acc[2][r]);
            float O = sigm(acc[3][r]);
            c[r] = fmaf(F, c[r], I * G);
            float hv = O * tanh2(c[r]);
            short hih = f2bf_tr(hv);
            short hlo = f2bf_tr(hv - b2f(hih));
            int s = lkhi * 4 + r;
            h_hi[p ^ 1][s * HSTR + u] = hih;
            h_lo[p ^ 1][s * HSTR + u] = hlo;
        }

        // ---- wave0 head: no shuffles needed ----
        if (w == 0 && l < 16) {
            float gp = acc5[0], ap = acc5[1], tp = acc5[2];
            if (t == 1) { gp = 1.f; ap = 1.f; tp = 1.f; }
            float ol = fmaf(x_lds[t * 16 + l], An, Cn);
            float z = ap * (ol - tp);
            float o = gp * softplusf(z) * frcp(ap);
            out_stage[t * 16 + l] = o;
            short oh = f2bf_tr(o);
            unsigned olo = (unsigned)(unsigned short)f2bf_tr(o - b2f(oh));
            op_pack[t & 1][l] = (unsigned)(unsigned short)oh | (olo << 16);
        }

        __syncthreads();  // h_t, out_t visible for step t+1
    }

    // ---- flush staged outputs: coalesced full-line writes ----
#pragma unroll
    for (int i = 0; i < 2; ++i) {
        int idx = tid + i * 512;  // 0..1023 vec4s
        int t = idx >> 2;
        int j4 = (idx & 3) << 2;
        f32x4 v = *(const f32x4*)(out_stage + t * 16 + j4);
        *(f32x4*)(out + (t * BB + b) * NN + n0 + j4) = v;
    }
}

extern "C" void kernel_launch(void* const* d_in, const int* in_sizes, int n_in,
                              void* d_out, int out_size, void* d_ws, size_t ws_size,
                              hipStream_t stream) {
    const float* in   = (const float*)d_in[0];
    const float* W_ih = (const float*)d_in[1];
    const float* b_ih = (const float*)d_in[2];
    const float* W_hh = (const float*)d_in[3];
    const float* b_hh = (const float*)d_in[4];
    const float* Wl   = (const float*)d_in[5];
    const float* bl   = (const float*)d_in[6];
    const float* W1   = (const float*)d_in[7];
    const float* b1   = (const float*)d_in[8];
    const float* W2   = (const float*)d_in[9];
    const float* b2   = (const float*)d_in[10];
    float* out = (float*)d_out;

    lstm_kernel<<<dim3(256), dim3(512), 0, stream>>>(
        in, W_ih, b_ih, W_hh, b_hh, Wl, bl, W1, b1, W2, b2, out);
}

// Round 4
// 399.772 us; speedup vs baseline: 2.1150x; 1.2897x over previous
//
#include <hip/hip_runtime.h>

#define TT 256
#define BB 32
#define NN 128
#define HH 128
#define HSTR 136  // fp16 elems; 272B rows -> 16B-aligned b128 frag reads

typedef __attribute__((ext_vector_type(8))) short short8;
typedef __attribute__((ext_vector_type(8))) _Float16 half8;
typedef __attribute__((ext_vector_type(4))) float f32x4;

__device__ __forceinline__ float frcp(float x) { return __builtin_amdgcn_rcpf(x); }
__device__ __forceinline__ float sigm(float x) { return frcp(1.f + __expf(-x)); }
__device__ __forceinline__ float tanh2(float x) {
    return fmaf(2.f, frcp(1.f + __expf(-2.f * x)), -1.f);
}
__device__ __forceinline__ float softplusf(float z) {
    return fmaxf(z, 0.f) + __logf(1.f + __expf(-fabsf(z)));
}

// Block: 512 threads = 8 waves, 16 sequences (batch b, neurons n0..n0+15).
// Wave w owns gate columns for units u = w*16 + (lane&15).
// fp16 2-product scheme: h rounded to fp16; W_hh kept exact as fp16 hi +
// 2048x-scaled fp16 residual accumulated separately (gate = acc1 + acc2/2048).
// Bias (b_ih+b_hh) enters via fp32 accumulator init (exact, free).
// Head gat = Wl @ h^T on wave 0 (swapped operands, bl via C-init).
__global__ __launch_bounds__(512, 1) void lstm_kernel(
    const float* __restrict__ in, const float* __restrict__ W_ih,
    const float* __restrict__ b_ih, const float* __restrict__ W_hh,
    const float* __restrict__ b_hh, const float* __restrict__ Wl,
    const float* __restrict__ bl, const float* __restrict__ W1,
    const float* __restrict__ b1, const float* __restrict__ W2,
    const float* __restrict__ b2, float* __restrict__ out)
{
    __shared__ __align__(16) _Float16 h_f16[2][16 * HSTR];
    __shared__ __align__(16) float x_lds[TT * 16];
    __shared__ __align__(16) float out_stage[TT * 16];
    __shared__ _Float16 op_f16[2][16];

    const int tid = threadIdx.x;
    const int w = tid >> 6, l = tid & 63;
    const int lrow = l & 15, lkhi = l >> 4;
    const int u = w * 16 + lrow;
    const int bid = blockIdx.x;
    // XCD-aware map: blocks sharing batch-row b (and output lines) -> same XCD
    const int b = bid & 31, n0 = (bid >> 5) << 4;

    // ---- stage x ----
    for (int i = tid; i < TT * 16; i += 512) {
        int t = i >> 4, j = i & 15;
        x_lds[i] = in[(t * BB + b) * NN + n0 + j];
    }

    // ---- W_hh.T fragments: exact fp16 hi + 2048x residual, reg resident ----
    half8 wh[4][4], wlo[4][4];
#pragma unroll
    for (int g = 0; g < 4; ++g)
#pragma unroll
        for (int kt = 0; kt < 4; ++kt) {
            const float* src = W_hh + (g * HH + u) * HH + kt * 32 + lkhi * 8;
            half8 hh, ll;
#pragma unroll
            for (int i = 0; i < 8; ++i) {
                float f = src[i];
                _Float16 h = (_Float16)f;
                hh[i] = h;
                ll[i] = (_Float16)((f - (float)h) * 2048.f);
            }
            wh[g][kt] = hh;
            wlo[g][kt] = ll;
        }

    // ---- ext tile B-frags: [wx, wo] fp16 (lanes l<16 carry k=0,1) ----
    half8 bext[4] = {};
    float bs[4];
#pragma unroll
    for (int g = 0; g < 4; ++g) {
        int j = g * HH + u;
        bs[g] = b_ih[j] + b_hh[j];
        if (l < 16) {
            bext[g][0] = (_Float16)W_ih[2 * j];
            bext[g][1] = (_Float16)W_ih[2 * j + 1];
        }
    }

    // ---- wave0: Wl fragments (rows >=3 zero), fp16, reg resident ----
    half8 wlv[4] = {};
    if (w == 0) {
#pragma unroll
        for (int kt = 0; kt < 4; ++kt)
#pragma unroll
            for (int i = 0; i < 8; ++i) {
                float f = (lrow < 3) ? Wl[lrow * HH + kt * 32 + lkhi * 8 + i] : 0.f;
                wlv[kt][i] = (_Float16)f;
            }
    }
    f32x4 blv;
#pragma unroll
    for (int r = 0; r < 4; ++r) {
        int row = lkhi * 4 + r;
        blv[r] = (row < 3) ? bl[row] : 0.f;
    }

    // ---- per-neuron affine MLP coeffs + t=0 output (wave0 head lanes) ----
    float An = 0.f, Cn = 0.f;
    if (w == 0 && l < 16) {
        int n = n0 + l;
#pragma unroll
        for (int k = 0; k < 10; ++k) {
            An = fmaf(W1[n * 10 + k], W2[n * 10 + k], An);
            Cn = fmaf(b1[n * 10 + k], W2[n * 10 + k], Cn);
        }
        Cn += b2[n];
        float x0 = in[b * NN + n0 + l];
        float o0 = softplusf(fmaf(x0, An, Cn) - 1.f);
        out_stage[l] = o0;
        op_f16[0][l] = (_Float16)o0;
    }

    for (int i = tid; i < 16 * HSTR; i += 512) {
        h_f16[0][i] = (_Float16)0.f;
        h_f16[1][i] = (_Float16)0.f;
    }
    float c[4] = {0.f, 0.f, 0.f, 0.f};
    __syncthreads();

    const float INV2048 = 4.8828125e-4f;

#pragma unroll 2
    for (int t = 1; t < TT; ++t) {
        const int p = (t - 1) & 1;

        // ---- h_{t-1} fragments (single fp16 plane) ----
        half8 ah[4];
#pragma unroll
        for (int kt = 0; kt < 4; ++kt)
            ah[kt] = *(const half8*)(&h_f16[p][lrow * HSTR + kt * 32 + lkhi * 8]);

        // ---- ext A-frag: [x_t, out_{t-1}] (lanes l<16) ----
        half8 aext = {};
        if (l < 16) {
            aext[0] = (_Float16)x_lds[t * 16 + l];
            aext[1] = op_f16[p][l];
        }

        // ---- gates: acc1 = bs + ext + h@Wh ; acc2 = h@(Wl*2048) ----
        f32x4 acc1[4], acc2[4];
#pragma unroll
        for (int g = 0; g < 4; ++g) {
            f32x4 a1 = {bs[g], bs[g], bs[g], bs[g]};
            f32x4 a2 = {0.f, 0.f, 0.f, 0.f};
            a1 = __builtin_amdgcn_mfma_f32_16x16x32_f16(aext, bext[g], a1, 0, 0, 0);
#pragma unroll
            for (int kt = 0; kt < 4; ++kt) {
                a1 = __builtin_amdgcn_mfma_f32_16x16x32_f16(ah[kt], wh[g][kt], a1, 0, 0, 0);
                a2 = __builtin_amdgcn_mfma_f32_16x16x32_f16(ah[kt], wlo[g][kt], a2, 0, 0, 0);
            }
            acc1[g] = a1;
            acc2[g] = a2;
        }

        // ---- wave0: gat = Wl @ h^T (+bl via C-init); lane s holds g,a,th ----
        f32x4 acc5 = blv;
        if (w == 0) {
#pragma unroll
            for (int kt = 0; kt < 4; ++kt)
                acc5 = __builtin_amdgcn_mfma_f32_16x16x32_f16(wlv[kt], ah[kt], acc5, 0, 0, 0);
        }

        // ---- gate nonlinearities + cell update + h_t write ----
#pragma unroll
        for (int r = 0; r < 4; ++r) {
            float gi = fmaf(acc2[0][r], INV2048, acc1[0][r]);
            float gf = fmaf(acc2[1][r], INV2048, acc1[1][r]);
            float gg = fmaf(acc2[2][r], INV2048, acc1[2][r]);
            float go = fmaf(acc2[3][r], INV2048, acc1[3][r]);
            float I = sigm(gi), F = sigm(gf), G = tanh2(gg), O = sigm(go);
            c[r] = fmaf(F, c[r], I * G);
            float hv = O * tanh2(c[r]);
            h_f16[p ^ 1][(lkhi * 4 + r) * HSTR + u] = (_Float16)hv;
        }

        // ---- wave0 head ----
        if (w == 0 && l < 16) {
            float gp = acc5[0], ap = acc5[1], tp = acc5[2];
            if (t == 1) { gp = 1.f; ap = 1.f; tp = 1.f; }
            float ol = fmaf(x_lds[t * 16 + l], An, Cn);
            float o = gp * softplusf(ap * (ol - tp)) * frcp(ap);
            out_stage[t * 16 + l] = o;
            op_f16[t & 1][l] = (_Float16)o;
        }

        __syncthreads();  // h_t, out_t visible for step t+1
    }

    // ---- flush staged outputs: coalesced full-line writes ----
#pragma unroll
    for (int i = 0; i < 2; ++i) {
        int idx = tid + i * 512;  // 0..1023 vec4s
        int t = idx >> 2;
        int j4 = (idx & 3) << 2;
        f32x4 v = *(const f32x4*)(out_stage + t * 16 + j4);
        *(f32x4*)(out + (t * BB + b) * NN + n0 + j4) = v;
    }
}

extern "C" void kernel_launch(void* const* d_in, const int* in_sizes, int n_in,
                              void* d_out, int out_size, void* d_ws, size_t ws_size,
                              hipStream_t stream) {
    const float* in   = (const float*)d_in[0];
    const float* W_ih = (const float*)d_in[1];
    const float* b_ih = (const float*)d_in[2];
    const float* W_hh = (const float*)d_in[3];
    const float* b_hh = (const float*)d_in[4];
    const float* Wl   = (const float*)d_in[5];
    const float* bl   = (const float*)d_in[6];
    const float* W1   = (const float*)d_in[7];
    const float* b1   = (const float*)d_in[8];
    const float* W2   = (const float*)d_in[9];
    const float* b2   = (const float*)d_in[10];
    float* out = (float*)d_out;

    lstm_kernel<<<dim3(256), dim3(512), 0, stream>>>(
        in, W_ih, b_ih, W_hh, b_hh, Wl, bl, W1, b1, W2, b2, out);
}

// Round 5
// 363.445 us; speedup vs baseline: 2.3264x; 1.1000x over previous
//
#include <hip/hip_runtime.h>

#define TT 256
#define BB 32
#define NN 128
#define HH 128
#define HSTR 136  // fp16 elems; 272B rows -> 16B-aligned b128 frag reads

typedef __attribute__((ext_vector_type(8))) _Float16 half8;
typedef __attribute__((ext_vector_type(4))) float f32x4;

__device__ __forceinline__ float frcp(float x) { return __builtin_amdgcn_rcpf(x); }
__device__ __forceinline__ float sigm(float x) { return frcp(1.f + __expf(-x)); }
__device__ __forceinline__ float tanh2(float x) {
    return fmaf(2.f, frcp(1.f + __expf(-2.f * x)), -1.f);
}
__device__ __forceinline__ float softplusf(float z) {
    return fmaxf(z, 0.f) + __logf(1.f + __expf(-fabsf(z)));
}

// Block: 512 threads = 8 waves, 16 sequences (batch b, neurons n0..n0+15).
// Wave w owns gate columns for units u = w*16 + (lane&15); thread-local i,f,g,o.
// W_hh as plain fp16 (RNE); bias exact via fp32 C-init. All waves redundantly
// compute the head tile (gat = Wl @ h^T) and the output head -> no straggler,
// out_prev is thread-local (no LDS round trip). MFMA order kt-outer/g-inner,
// ext (x2) tile last so out_prev binds late in the chain.
__global__ __launch_bounds__(512, 1) void lstm_kernel(
    const float* __restrict__ in, const float* __restrict__ W_ih,
    const float* __restrict__ b_ih, const float* __restrict__ W_hh,
    const float* __restrict__ b_hh, const float* __restrict__ Wl,
    const float* __restrict__ bl, const float* __restrict__ W1,
    const float* __restrict__ b1, const float* __restrict__ W2,
    const float* __restrict__ b2, float* __restrict__ out)
{
    __shared__ __align__(16) _Float16 h_f16[2][16 * HSTR];
    __shared__ __align__(16) float x_lds[TT * 16];
    __shared__ __align__(16) float out_stage[TT * 16];

    const int tid = threadIdx.x;
    const int w = tid >> 6, l = tid & 63;
    const int lrow = l & 15, lkhi = l >> 4;
    const int u = w * 16 + lrow;
    const int bid = blockIdx.x;
    // XCD-aware map: blocks sharing batch-row b (and output lines) -> same XCD
    const int b = bid & 31, n0 = (bid >> 5) << 4;

    // ---- stage x ----
    for (int i = tid; i < TT * 16; i += 512) {
        int t = i >> 4, j = i & 15;
        x_lds[i] = in[(t * BB + b) * NN + n0 + j];
    }

    // ---- W_hh.T fragments, fp16 RNE, register resident ----
    half8 wh[4][4];
#pragma unroll
    for (int g = 0; g < 4; ++g)
#pragma unroll
        for (int kt = 0; kt < 4; ++kt) {
            const float* src = W_hh + (g * HH + u) * HH + kt * 32 + lkhi * 8;
            half8 hh;
#pragma unroll
            for (int i = 0; i < 8; ++i) hh[i] = (_Float16)src[i];
            wh[g][kt] = hh;
        }

    // ---- ext tile B-frags: [wx, wo] fp16 (lanes l<16 carry k=0,1) ----
    half8 bext[4] = {};
    float bs[4];
#pragma unroll
    for (int g = 0; g < 4; ++g) {
        int j = g * HH + u;
        bs[g] = b_ih[j] + b_hh[j];
        if (l < 16) {
            bext[g][0] = (_Float16)W_ih[2 * j];
            bext[g][1] = (_Float16)W_ih[2 * j + 1];
        }
    }

    // ---- Wl fragments (rows >=3 zero), fp16, all waves ----
    half8 wlv[4] = {};
#pragma unroll
    for (int kt = 0; kt < 4; ++kt)
#pragma unroll
        for (int i = 0; i < 8; ++i) {
            float f = (lrow < 3) ? Wl[lrow * HH + kt * 32 + lkhi * 8 + i] : 0.f;
            wlv[kt][i] = (_Float16)f;
        }
    f32x4 blv;
#pragma unroll
    for (int r = 0; r < 4; ++r) {
        int row = lkhi * 4 + r;
        blv[r] = (row < 3) ? bl[row] : 0.f;
    }

    // ---- per-neuron affine MLP coeffs + t=0 output (all waves, lanes<16) ----
    float An = 0.f, Cn = 0.f;
    _Float16 op_next = (_Float16)0.f;
    if (l < 16) {
        int n = n0 + l;
#pragma unroll
        for (int k = 0; k < 10; ++k) {
            An = fmaf(W1[n * 10 + k], W2[n * 10 + k], An);
            Cn = fmaf(b1[n * 10 + k], W2[n * 10 + k], Cn);
        }
        Cn += b2[n];
        float x0 = in[b * NN + n0 + l];
        float o0 = softplusf(fmaf(x0, An, Cn) - 1.f);
        if (w == 0) out_stage[l] = o0;
        op_next = (_Float16)o0;
    }

    for (int i = tid; i < 16 * HSTR; i += 512) {
        h_f16[0][i] = (_Float16)0.f;
        h_f16[1][i] = (_Float16)0.f;
    }
    float c[4] = {0.f, 0.f, 0.f, 0.f};
    __syncthreads();

#pragma unroll 2
    for (int t = 1; t < TT; ++t) {
        const int p = (t - 1) & 1;

        // ---- h_{t-1} fragments (single fp16 plane) ----
        half8 ah[4];
#pragma unroll
        for (int kt = 0; kt < 4; ++kt)
            ah[kt] = *(const half8*)(&h_f16[p][lrow * HSTR + kt * 32 + lkhi * 8]);

        // ---- ext A-frag: [x_t, out_{t-1}] (lanes l<16), op thread-local ----
        half8 aext = {};
        if (l < 16) {
            aext[0] = (_Float16)x_lds[t * 16 + l];
            aext[1] = op_next;
        }

        // ---- gates + head tile: kt-outer, 5 independent MFMAs per kt ----
        f32x4 acc[4];
#pragma unroll
        for (int g = 0; g < 4; ++g) acc[g] = (f32x4){bs[g], bs[g], bs[g], bs[g]};
        f32x4 acc5 = blv;
#pragma unroll
        for (int kt = 0; kt < 4; ++kt) {
#pragma unroll
            for (int g = 0; g < 4; ++g)
                acc[g] = __builtin_amdgcn_mfma_f32_16x16x32_f16(ah[kt], wh[g][kt], acc[g], 0, 0, 0);
            acc5 = __builtin_amdgcn_mfma_f32_16x16x32_f16(wlv[kt], ah[kt], acc5, 0, 0, 0);
        }
#pragma unroll
        for (int g = 0; g < 4; ++g)
            acc[g] = __builtin_amdgcn_mfma_f32_16x16x32_f16(aext, bext[g], acc[g], 0, 0, 0);

        // ---- gate nonlinearities + cell update + h_t write ----
#pragma unroll
        for (int r = 0; r < 4; ++r) {
            float I = sigm(acc[0][r]);
            float F = sigm(acc[1][r]);
            float G = tanh2(acc[2][r]);
            float O = sigm(acc[3][r]);
            c[r] = fmaf(F, c[r], I * G);
            float hv = O * tanh2(c[r]);
            h_f16[p ^ 1][(lkhi * 4 + r) * HSTR + u] = (_Float16)hv;
        }

        // ---- head (all waves, lanes<16): lane s holds g,a,th in acc5[0..2] ----
        if (l < 16) {
            float gp = acc5[0], ap = acc5[1], tp = acc5[2];
            if (t == 1) { gp = 1.f; ap = 1.f; tp = 1.f; }
            float ol = fmaf(x_lds[t * 16 + l], An, Cn);
            float o = gp * softplusf(ap * (ol - tp)) * frcp(ap);
            if (w == 0) out_stage[t * 16 + l] = o;
            op_next = (_Float16)o;
        }

        __syncthreads();  // h_t visible for step t+1
    }

    // ---- flush staged outputs: coalesced full-line writes ----
#pragma unroll
    for (int i = 0; i < 2; ++i) {
        int idx = tid + i * 512;  // 0..1023 vec4s
        int t = idx >> 2;
        int j4 = (idx & 3) << 2;
        f32x4 v = *(const f32x4*)(out_stage + t * 16 + j4);
        *(f32x4*)(out + (t * BB + b) * NN + n0 + j4) = v;
    }
}

extern "C" void kernel_launch(void* const* d_in, const int* in_sizes, int n_in,
                              void* d_out, int out_size, void* d_ws, size_t ws_size,
                              hipStream_t stream) {
    const float* in   = (const float*)d_in[0];
    const float* W_ih = (const float*)d_in[1];
    const float* b_ih = (const float*)d_in[2];
    const float* W_hh = (const float*)d_in[3];
    const float* b_hh = (const float*)d_in[4];
    const float* Wl   = (const float*)d_in[5];
    const float* bl   = (const float*)d_in[6];
    const float* W1   = (const float*)d_in[7];
    const float* b1   = (const float*)d_in[8];
    const float* W2   = (const float*)d_in[9];
    const float* b2   = (const float*)d_in[10];
    float* out = (float*)d_out;

    lstm_kernel<<<dim3(256), dim3(512), 0, stream>>>(
        in, W_ih, b_ih, W_hh, b_hh, Wl, bl, W1, b1, W2, b2, out);
}

// Round 6
// 333.097 us; speedup vs baseline: 2.5383x; 1.0911x over previous
//
#include <hip/hip_runtime.h>

#define TT 256
#define BB 32
#define NN 128
#define HH 128
#define HSTR 136  // fp16 elems; 272B rows -> 16B-aligned b128 frag reads

typedef __attribute__((ext_vector_type(8))) _Float16 half8;
typedef __attribute__((ext_vector_type(4))) float f32x4;

#define L2E 1.4426950408889634f   // log2(e)
#define C2L2E 2.8853900817779268f // 2*log2(e)

__device__ __forceinline__ float frcp(float x) { return __builtin_amdgcn_rcpf(x); }
__device__ __forceinline__ float fexp2(float x) { return __builtin_amdgcn_exp2f(x); }
__device__ __forceinline__ float flog2(float x) { return __builtin_amdgcn_logf(x); }

// softplus(a*z)/a with a' = a*log2e pre-scaled:  log2(1+2^(a'*z)) / a'
__device__ __forceinline__ float head_out(float gp, float apr, float zz) {
    float zp = apr * zz;
    float sp = fmaxf(zp, 0.f) + flog2(1.f + fexp2(-fabsf(zp)));
    return gp * sp * frcp(apr);
}

// Block: 512 threads = 8 waves, 16 sequences (batch b, neurons n0..n0+15).
// Wave w owns gate columns for units u = w*16 + (lane&15); thread-local i,f,g,o.
// Gate weights/biases pre-scaled by log2e (2*log2e for g-gate); cell state c is
// kept scaled by 2*log2e so every exponential is a bare v_exp_f32 (exp2).
// Bias enters as the C operand of the first MFMA (no per-step acc init movs).
// All waves redundantly compute the head tile (gat = Wl @ h^T, swapped operands)
// so out_prev stays thread-local; Wl alpha-row pre-scaled by log2e.
__global__ __launch_bounds__(512, 1) void lstm_kernel(
    const float* __restrict__ in, const float* __restrict__ W_ih,
    const float* __restrict__ b_ih, const float* __restrict__ W_hh,
    const float* __restrict__ b_hh, const float* __restrict__ Wl,
    const float* __restrict__ bl, const float* __restrict__ W1,
    const float* __restrict__ b1, const float* __restrict__ W2,
    const float* __restrict__ b2, float* __restrict__ out)
{
    __shared__ __align__(16) _Float16 h_f16[2][16 * HSTR];
    __shared__ __align__(16) float x_lds[TT * 16];
    __shared__ __align__(16) float out_stage[TT * 16];

    const int tid = threadIdx.x;
    const int w = tid >> 6, l = tid & 63;
    const int lrow = l & 15, lkhi = l >> 4;
    const int u = w * 16 + lrow;
    const int bid = blockIdx.x;
    // XCD-aware map: blocks sharing batch-row b (and output lines) -> same XCD
    const int b = bid & 31, n0 = (bid >> 5) << 4;

    const float sg[4] = {L2E, L2E, C2L2E, L2E};  // per-gate exp2 prescale

    // ---- stage x ----
    for (int i = tid; i < TT * 16; i += 512) {
        int t = i >> 4, j = i & 15;
        x_lds[i] = in[(t * BB + b) * NN + n0 + j];
    }

    // ---- W_hh.T fragments, fp16 RNE, pre-scaled, register resident ----
    half8 wh[4][4];
#pragma unroll
    for (int g = 0; g < 4; ++g)
#pragma unroll
        for (int kt = 0; kt < 4; ++kt) {
            const float* src = W_hh + (g * HH + u) * HH + kt * 32 + lkhi * 8;
            half8 hh;
#pragma unroll
            for (int i = 0; i < 8; ++i) hh[i] = (_Float16)(src[i] * sg[g]);
            wh[g][kt] = hh;
        }

    // ---- ext tile B-frags [wx,wo] (pre-scaled) + bias quads (fp32, exact) ----
    half8 bext[4] = {};
    f32x4 bs4[4];
#pragma unroll
    for (int g = 0; g < 4; ++g) {
        int j = g * HH + u;
        float bsv = (b_ih[j] + b_hh[j]) * sg[g];
        bs4[g] = (f32x4){bsv, bsv, bsv, bsv};
        if (l < 16) {
            bext[g][0] = (_Float16)(W_ih[2 * j] * sg[g]);
            bext[g][1] = (_Float16)(W_ih[2 * j + 1] * sg[g]);
        }
    }

    // ---- Wl fragments (rows >=3 zero; alpha row *L2E), fp16, all waves ----
    half8 wlv[4] = {};
    const float wlsc = (lrow == 1) ? L2E : 1.f;
#pragma unroll
    for (int kt = 0; kt < 4; ++kt)
#pragma unroll
        for (int i = 0; i < 8; ++i) {
            float f = (lrow < 3) ? Wl[lrow * HH + kt * 32 + lkhi * 8 + i] * wlsc : 0.f;
            wlv[kt][i] = (_Float16)f;
        }
    f32x4 blv;
#pragma unroll
    for (int r = 0; r < 4; ++r) {
        int row = lkhi * 4 + r;
        blv[r] = (row < 3) ? bl[row] * ((row == 1) ? L2E : 1.f) : 0.f;
    }

    // ---- per-neuron affine MLP coeffs + t=0 output (all waves, lanes<16) ----
    float An = 0.f, Cn = 0.f;
    _Float16 op_next = (_Float16)0.f;
    if (l < 16) {
        int n = n0 + l;
#pragma unroll
        for (int k = 0; k < 10; ++k) {
            An = fmaf(W1[n * 10 + k], W2[n * 10 + k], An);
            Cn = fmaf(b1[n * 10 + k], W2[n * 10 + k], Cn);
        }
        Cn += b2[n];
        float x0 = in[b * NN + n0 + l];
        float o0 = head_out(1.f, L2E, fmaf(x0, An, Cn) - 1.f);
        if (w == 0) out_stage[l] = o0;
        op_next = (_Float16)o0;
    }

    for (int i = tid; i < 16 * HSTR; i += 512) {
        h_f16[0][i] = (_Float16)0.f;
        h_f16[1][i] = (_Float16)0.f;
    }
    float c[4] = {0.f, 0.f, 0.f, 0.f};  // scaled by 2*log2e
    __syncthreads();

#pragma unroll 2
    for (int t = 1; t < TT; ++t) {
        const int p = (t - 1) & 1;

        // ---- h_{t-1} fragments (single fp16 plane) ----
        half8 ah[4];
#pragma unroll
        for (int kt = 0; kt < 4; ++kt)
            ah[kt] = *(const half8*)(&h_f16[p][lrow * HSTR + kt * 32 + lkhi * 8]);

        // ---- ext A-frag: [x_t, out_{t-1}] (lanes l<16), op thread-local ----
        half8 aext = {};
        if (l < 16) {
            aext[0] = (_Float16)x_lds[t * 16 + l];
            aext[1] = op_next;
        }

        // ---- gates: ext first with C=bias quad; then kt-outer/g-inner ----
        f32x4 acc[4];
#pragma unroll
        for (int g = 0; g < 4; ++g)
            acc[g] = __builtin_amdgcn_mfma_f32_16x16x32_f16(aext, bext[g], bs4[g], 0, 0, 0);
        f32x4 acc5 = __builtin_amdgcn_mfma_f32_16x16x32_f16(wlv[0], ah[0], blv, 0, 0, 0);
#pragma unroll
        for (int kt = 0; kt < 4; ++kt) {
#pragma unroll
            for (int g = 0; g < 4; ++g)
                acc[g] = __builtin_amdgcn_mfma_f32_16x16x32_f16(ah[kt], wh[g][kt], acc[g], 0, 0, 0);
            if (kt > 0)
                acc5 = __builtin_amdgcn_mfma_f32_16x16x32_f16(wlv[kt], ah[kt], acc5, 0, 0, 0);
        }

        // ---- nonlinearities: 5 exp2 + 3 rcp per row, inf-safe ----
#pragma unroll
        for (int r = 0; r < 4; ++r) {
            float ei = fexp2(-acc[0][r]);
            float ef = fexp2(-acc[1][r]);
            float eg = fminf(fexp2(-acc[2][r]), 1e30f);
            float eo = fexp2(-acc[3][r]);
            float num = fmaf(-C2L2E, eg, C2L2E);          // 2L2E*(1-eg)
            float IG = num * frcp((1.f + ei) * (1.f + eg));
            float F = frcp(1.f + ef);
            c[r] = fmaf(F, c[r], IG);                     // c scaled by 2L2E
            float ec = fminf(fexp2(-c[r]), 1e30f);
            float hv = (1.f - ec) * frcp((1.f + eo) * (1.f + ec));
            h_f16[p ^ 1][(lkhi * 4 + r) * HSTR + u] = (_Float16)hv;
        }

        // ---- head (all waves, lanes<16): lane s holds g,a',th in acc5[0..2] ----
        if (l < 16) {
            float gp = acc5[0], apr = acc5[1], tp = acc5[2];
            if (t == 1) { gp = 1.f; apr = L2E; tp = 1.f; }
            float ol = fmaf(x_lds[t * 16 + l], An, Cn);
            float o = head_out(gp, apr, ol - tp);
            if (w == 0) out_stage[t * 16 + l] = o;
            op_next = (_Float16)o;
        }

        __syncthreads();  // h_t visible for step t+1
    }

    // ---- flush staged outputs: coalesced full-line writes ----
#pragma unroll
    for (int i = 0; i < 2; ++i) {
        int idx = tid + i * 512;  // 0..1023 vec4s
        int t = idx >> 2;
        int j4 = (idx & 3) << 2;
        f32x4 v = *(const f32x4*)(out_stage + t * 16 + j4);
        *(f32x4*)(out + (t * BB + b) * NN + n0 + j4) = v;
    }
}

extern "C" void kernel_launch(void* const* d_in, const int* in_sizes, int n_in,
                              void* d_out, int out_size, void* d_ws, size_t ws_size,
                              hipStream_t stream) {
    const float* in   = (const float*)d_in[0];
    const float* W_ih = (const float*)d_in[1];
    const float* b_ih = (const float*)d_in[2];
    const float* W_hh = (const float*)d_in[3];
    const float* b_hh = (const float*)d_in[4];
    const float* Wl   = (const float*)d_in[5];
    const float* bl   = (const float*)d_in[6];
    const float* W1   = (const float*)d_in[7];
    const float* b1   = (const float*)d_in[8];
    const float* W2   = (const float*)d_in[9];
    const float* b2   = (const float*)d_in[10];
    float* out = (float*)d_out;

    lstm_kernel<<<dim3(256), dim3(512), 0, stream>>>(
        in, W_ih, b_ih, W_hh, b_hh, Wl, bl, W1, b1, W2, b2, out);
}

// Round 7
// 285.973 us; speedup vs baseline: 2.9566x; 1.1648x over previous
//
#include <hip/hip_runtime.h>

#define TT 256
#define BB 32
#define NN 128
#define HH 128
#define HSTR 136  // fp16 elems; 272B rows -> 16B-aligned b128 frag reads

typedef __attribute__((ext_vector_type(8))) _Float16 half8;
typedef __attribute__((ext_vector_type(4))) float f32x4;

#define L2E 1.4426950408889634f   // log2(e)
#define C2L2E 2.8853900817779268f // 2*log2(e)

__device__ __forceinline__ float frcp(float x) { return __builtin_amdgcn_rcpf(x); }
__device__ __forceinline__ float fexp2(float x) { return __builtin_amdgcn_exp2f(x); }
__device__ __forceinline__ float flog2(float x) { return __builtin_amdgcn_logf(x); }

// softplus(a*z)/a with a' = a*log2e pre-scaled:  log2(1+2^(a'*z)) / a'
__device__ __forceinline__ float head_out(float gp, float apr, float zz) {
    float zp = apr * zz;
    float sp = fmaxf(zp, 0.f) + flog2(1.f + fexp2(-fabsf(zp)));
    return gp * sp * frcp(apr);
}

// Block: 512 threads = 8 waves, 16 sequences (batch b, neurons n0..n0+15).
// Wave w owns gate columns for units u = w*16 + (lane&15); thread-local i,f,g,o.
// Weights pre-scaled by log2e (2*log2e for g-gate); cell state c scaled by
// 2*log2e so every exponential is a bare v_exp_f32. Window schedule: ext MFMAs
// (no LDS dep, aext prebuilt last window) -> h ds_reads -> acc5 chain -> gate
// MFMAs with head NL co-issued under them -> core NL (merged-F single rcp) ->
// h writes -> barrier. x(t+1) prefetched + aext(t+1) built pre-barrier.
__global__ __launch_bounds__(512, 1) void lstm_kernel(
    const float* __restrict__ in, const float* __restrict__ W_ih,
    const float* __restrict__ b_ih, const float* __restrict__ W_hh,
    const float* __restrict__ b_hh, const float* __restrict__ Wl,
    const float* __restrict__ bl, const float* __restrict__ W1,
    const float* __restrict__ b1, const float* __restrict__ W2,
    const float* __restrict__ b2, float* __restrict__ out)
{
    __shared__ __align__(16) _Float16 h_f16[2][16 * HSTR];
    __shared__ __align__(16) float x_lds[TT * 16];
    __shared__ __align__(16) float out_stage[TT * 16];

    const int tid = threadIdx.x;
    const int w = tid >> 6, l = tid & 63;
    const int lrow = l & 15, lkhi = l >> 4;
    const int u = w * 16 + lrow;
    const int bid = blockIdx.x;
    // XCD-aware map: blocks sharing batch-row b (and output lines) -> same XCD
    const int b = bid & 31, n0 = (bid >> 5) << 4;

    const float sg[4] = {L2E, L2E, C2L2E, L2E};  // per-gate exp2 prescale

    // ---- stage x ----
    for (int i = tid; i < TT * 16; i += 512) {
        int t = i >> 4, j = i & 15;
        x_lds[i] = in[(t * BB + b) * NN + n0 + j];
    }

    // ---- W_hh.T fragments, fp16 RNE, pre-scaled, register resident ----
    half8 wh[4][4];
#pragma unroll
    for (int g = 0; g < 4; ++g)
#pragma unroll
        for (int kt = 0; kt < 4; ++kt) {
            const float* src = W_hh + (g * HH + u) * HH + kt * 32 + lkhi * 8;
            half8 hh;
#pragma unroll
            for (int i = 0; i < 8; ++i) hh[i] = (_Float16)(src[i] * sg[g]);
            wh[g][kt] = hh;
        }

    // ---- ext tile B-frags [wx,wo] (pre-scaled) + bias quads (fp32, exact) ----
    half8 bext[4] = {};
    f32x4 bs4[4];
#pragma unroll
    for (int g = 0; g < 4; ++g) {
        int j = g * HH + u;
        float bsv = (b_ih[j] + b_hh[j]) * sg[g];
        bs4[g] = (f32x4){bsv, bsv, bsv, bsv};
        if (l < 16) {
            bext[g][0] = (_Float16)(W_ih[2 * j] * sg[g]);
            bext[g][1] = (_Float16)(W_ih[2 * j + 1] * sg[g]);
        }
    }

    // ---- Wl fragments (rows >=3 zero; alpha row *L2E), fp16, all waves ----
    half8 wlv[4] = {};
    const float wlsc = (lrow == 1) ? L2E : 1.f;
#pragma unroll
    for (int kt = 0; kt < 4; ++kt)
#pragma unroll
        for (int i = 0; i < 8; ++i) {
            float f = (lrow < 3) ? Wl[lrow * HH + kt * 32 + lkhi * 8 + i] * wlsc : 0.f;
            wlv[kt][i] = (_Float16)f;
        }
    f32x4 blv;
#pragma unroll
    for (int r = 0; r < 4; ++r) {
        int row = lkhi * 4 + r;
        blv[r] = (row < 3) ? bl[row] * ((row == 1) ? L2E : 1.f) : 0.f;
    }

    // ---- per-neuron affine MLP coeffs + t=0 output + t=1 ext prep ----
    float An = 0.f, Cn = 0.f;
    float xv = 0.f;            // x(t) carried across windows (lanes<16)
    half8 aext = {};           // ext A-frag for the upcoming window
    if (l < 16) {
        int n = n0 + l;
#pragma unroll
        for (int k = 0; k < 10; ++k) {
            An = fmaf(W1[n * 10 + k], W2[n * 10 + k], An);
            Cn = fmaf(b1[n * 10 + k], W2[n * 10 + k], Cn);
        }
        Cn += b2[n];
        float x0 = in[b * NN + n0 + l];
        float o0 = head_out(1.f, L2E, fmaf(x0, An, Cn) - 1.f);
        if (w == 0) out_stage[l] = o0;
        xv = in[(BB + b) * NN + n0 + l];   // x(1)
        aext[0] = (_Float16)xv;
        aext[1] = (_Float16)o0;
    }

    for (int i = tid; i < 16 * HSTR; i += 512) {
        h_f16[0][i] = (_Float16)0.f;
        h_f16[1][i] = (_Float16)0.f;
    }
    float c[4] = {0.f, 0.f, 0.f, 0.f};  // scaled by 2*log2e
    __syncthreads();

#pragma unroll 2
    for (int t = 1; t < TT; ++t) {
        const int p = (t - 1) & 1;

        // ---- ext MFMAs first: no LDS dependency, cover h-read latency ----
        f32x4 acc[4];
#pragma unroll
        for (int g = 0; g < 4; ++g)
            acc[g] = __builtin_amdgcn_mfma_f32_16x16x32_f16(aext, bext[g], bs4[g], 0, 0, 0);

        // ---- h_{t-1} fragments ----
        half8 ah[4];
#pragma unroll
        for (int kt = 0; kt < 4; ++kt)
            ah[kt] = *(const half8*)(&h_f16[p][lrow * HSTR + kt * 32 + lkhi * 8]);

        // ---- head tile chain early so head NL can overlap gate MFMAs ----
        f32x4 acc5 = __builtin_amdgcn_mfma_f32_16x16x32_f16(wlv[0], ah[0], blv, 0, 0, 0);
#pragma unroll
        for (int kt = 1; kt < 4; ++kt)
            acc5 = __builtin_amdgcn_mfma_f32_16x16x32_f16(wlv[kt], ah[kt], acc5, 0, 0, 0);

        // ---- gate MFMAs ----
#pragma unroll
        for (int kt = 0; kt < 4; ++kt)
#pragma unroll
            for (int g = 0; g < 4; ++g)
                acc[g] = __builtin_amdgcn_mfma_f32_16x16x32_f16(ah[kt], wh[g][kt], acc[g], 0, 0, 0);

        // ---- head + next-window prep (lanes<16): co-issues under gate MFMAs ----
        if (l < 16) {
            float gp = acc5[0], apr = acc5[1], tp = acc5[2];
            if (t == 1) { gp = 1.f; apr = L2E; tp = 1.f; }
            float ol = fmaf(xv, An, Cn);
            float o = head_out(gp, apr, ol - tp);
            if (w == 0) out_stage[t * 16 + l] = o;
            int tn = (t < TT - 1) ? t + 1 : t;
            xv = x_lds[tn * 16 + l];          // prefetch x(t+1)
            aext[0] = (_Float16)xv;
            aext[1] = (_Float16)o;            // out_t
        }

        // ---- core NL: merged-F (5 exp2 + 2 rcp per cell) ----
#pragma unroll
        for (int r = 0; r < 4; ++r) {
            float ei = fexp2(-acc[0][r]);
            float ef = fexp2(-acc[1][r]);
            float eg = fminf(fexp2(-acc[2][r]), 1e30f);
            float eo = fexp2(-acc[3][r]);
            float Dig = (1.f + ei) * (1.f + eg);
            float num = fmaf(-C2L2E, eg, C2L2E);     // 2L2E*(1-eg)
            float fe1 = 1.f + ef;
            float numer = fmaf(c[r], Dig, num * fe1);
            c[r] = numer * frcp(fe1 * Dig);          // c scaled by 2L2E
            float ec = fminf(fexp2(-c[r]), 1e30f);
            float hv = (1.f - ec) * frcp((1.f + eo) * (1.f + ec));
            h_f16[p ^ 1][(lkhi * 4 + r) * HSTR + u] = (_Float16)hv;
        }

        __syncthreads();  // h_t visible for step t+1
    }

    // ---- flush staged outputs: coalesced full-line writes ----
#pragma unroll
    for (int i = 0; i < 2; ++i) {
        int idx = tid + i * 512;  // 0..1023 vec4s
        int t = idx >> 2;
        int j4 = (idx & 3) << 2;
        f32x4 v = *(const f32x4*)(out_stage + t * 16 + j4);
        *(f32x4*)(out + (t * BB + b) * NN + n0 + j4) = v;
    }
}

extern "C" void kernel_launch(void* const* d_in, const int* in_sizes, int n_in,
                              void* d_out, int out_size, void* d_ws, size_t ws_size,
                              hipStream_t stream) {
    const float* in   = (const float*)d_in[0];
    const float* W_ih = (const float*)d_in[1];
    const float* b_ih = (const float*)d_in[2];
    const float* W_hh = (const float*)d_in[3];
    const float* b_hh = (const float*)d_in[4];
    const float* Wl   = (const float*)d_in[5];
    const float* bl   = (const float*)d_in[6];
    const float* W1   = (const float*)d_in[7];
    const float* b1   = (const float*)d_in[8];
    const float* W2   = (const float*)d_in[9];
    const float* b2   = (const float*)d_in[10];
    float* out = (float*)d_out;

    lstm_kernel<<<dim3(256), dim3(512), 0, stream>>>(
        in, W_ih, b_ih, W_hh, b_hh, Wl, bl, W1, b1, W2, b2, out);
}